// Round 3
// baseline (1142.737 us; speedup 1.0000x reference)
//
#include <hip/hip_runtime.h>
#include <hip/hip_bf16.h>

// LSTMblock: 2-layer, 8-head LSTM (H=F=64, T=12) over N=16384 independent
// nodes, then 1x1 conv mixing (head,t) channels (96 -> 12). Inputs fp32,
// output fp32 (proven R2: fp32 stores validated). Internal: bf16 MFMA,
// fp32 cell math.
//
// R3 structure: heads are independent (conv is the only coupling) -> grid
// 1024 node-tiles x 8 heads = 8192 blocks. Each block runs ONE head's
// 2-layer recurrence on 16 nodes (24 barrier-halves instead of R2's 192)
// and streams h_t (bf16, same rounding as the recurrence itself) to a
// 201 MB ws slab laid out (head*T + t, N, 64) = conv channel-major.
// conv_reduce then computes out[o] = sum_c cw[o][c]*hs[c] + cb[o].
// Fallback to the proven monolithic kernel if ws is too small.
//
// MFMA v_mfma_f32_16x16x32_bf16 lane mapping (m89/m120-verified):
//   A[m][k]: lane(quad,col) reg j holds A[m=col][k=quad*8+j]
//   B[k][n]: lane reg j holds B[k=quad*8+j][n=col]
//   D[m][n]: lane reg r holds D[m=quad*4+r][n=col]

#define T_LEN 12
#define NHEADS 8
#define HD 64
#define NNODES 16384
#define MT 16
#define LDSP 72

typedef __bf16 bf16_t;
typedef __attribute__((ext_vector_type(4))) __bf16 bf16x4;
typedef __attribute__((ext_vector_type(8))) __bf16 bf16x8;
typedef __attribute__((ext_vector_type(4))) float f32x4;

#define MFMA16(a, b, c) __builtin_amdgcn_mfma_f32_16x16x32_bf16((a), (b), (c), 0, 0, 0)

__device__ __forceinline__ float fast_sigmoid(float v) {
    return __builtin_amdgcn_rcpf(1.0f + __expf(-v));
}
__device__ __forceinline__ float fast_tanh(float v) {
    return 2.0f * __builtin_amdgcn_rcpf(1.0f + __expf(-2.0f * v)) - 1.0f;
}

__device__ __forceinline__ bf16x8 load8f(const float* p) {
    f32x4 a = *(const f32x4*)p;
    f32x4 b = *(const f32x4*)(p + 4);
    bf16x8 r;
    r[0] = (bf16_t)a[0]; r[1] = (bf16_t)a[1]; r[2] = (bf16_t)a[2]; r[3] = (bf16_t)a[3];
    r[4] = (bf16_t)b[0]; r[5] = (bf16_t)b[1]; r[6] = (bf16_t)b[2]; r[7] = (bf16_t)b[3];
    return r;
}

// ================= kernel 1: per-(tile,head) 2-layer LSTM =================
__global__ __launch_bounds__(256) void lstm_head_kernel(
    const float* __restrict__ xg,   // (T, N, 64)
    const float* __restrict__ Wih,  // (2, 8, 256, 64)
    const float* __restrict__ Whh,  // (2, 8, 256, 64)
    const float* __restrict__ bih,  // (2, 8, 256)
    const float* __restrict__ bhh,  // (2, 8, 256)
    const float* __restrict__ h0g,  // (8, 2, N, 64)
    const float* __restrict__ c0g,  // (8, 2, N, 64)
    bf16_t* __restrict__ hsw)       // (8*T, N, 64) channel-major hs
{
    __shared__ __align__(16) bf16_t hA[2][2][MT][LDSP];  // [layer][buf][node][h]

    const int tid  = threadIdx.x;
    const int w    = tid >> 6;     // wave id: owns H-slice [16w, 16w+16)
    const int lane = tid & 63;
    const int quad = lane >> 4;
    const int col  = lane & 15;
    const int a    = blockIdx.x & (NHEADS - 1);
    const int nb   = (blockIdx.x >> 3) * MT;

    // ---- per-head weight B-fragments, register-resident ----
    bf16x8 wih[2][4][2], whh[2][4][2];   // [layer][gate i/f/g/o][kfrag]
    #pragma unroll
    for (int l = 0; l < 2; ++l)
        #pragma unroll
        for (int ni = 0; ni < 4; ++ni)
            #pragma unroll
            for (int kf = 0; kf < 2; ++kf) {
                size_t off = (((size_t)l * NHEADS + a) * 256 + (4 * ni + w) * 16 + col) * HD
                           + kf * 32 + quad * 8;
                wih[l][ni][kf] = load8f(Wih + off);
                whh[l][ni][kf] = load8f(Whh + off);
            }
    float bias[2][4];
    #pragma unroll
    for (int l = 0; l < 2; ++l)
        #pragma unroll
        for (int ni = 0; ni < 4; ++ni) {
            int off = (l * NHEADS + a) * 256 + ni * 64 + w * 16 + col;
            bias[l][ni] = bih[off] + bhh[off];
        }
    float creg[2][4];
    #pragma unroll
    for (int l = 0; l < 2; ++l)
        #pragma unroll
        for (int r = 0; r < 4; ++r)
            creg[l][r] = c0g[(((size_t)a * 2 + l) * NNODES + nb + quad * 4 + r) * HD
                             + w * 16 + col];
    // h0 -> hA[*][0]  (2048 elems, one 8-elem chunk per thread)
    {
        int e    = tid * 8;
        int l    = e >> 10;
        int node = (e >> 6) & (MT - 1);
        int hh   = e & (HD - 1);
        *(bf16x8*)&hA[l][0][node][hh] =
            load8f(h0g + (((size_t)a * 2 + l) * NNODES + nb + node) * HD + hh);
    }
    __syncthreads();

    // x A-fragments straight from global, software-prefetched one step ahead
    bf16x8 xa0 = load8f(xg + ((size_t)0 * NNODES + nb + col) * HD + quad * 8);
    bf16x8 xa1 = load8f(xg + ((size_t)0 * NNODES + nb + col) * HD + 32 + quad * 8);

    int cur = 0;
    #pragma unroll 1
    for (int t = 0; t < T_LEN; ++t) {
        // ---------- layer 0: gates = x_t*Wih0^T + h0*Whh0^T ----------
        bf16x8 ha0 = *(const bf16x8*)&hA[0][cur][col][quad * 8];
        bf16x8 ha1 = *(const bf16x8*)&hA[0][cur][col][32 + quad * 8];
        f32x4 acc[4];
        #pragma unroll
        for (int ni = 0; ni < 4; ++ni) {
            f32x4 z = {0.f, 0.f, 0.f, 0.f};
            z = MFMA16(xa0, wih[0][ni][0], z);
            z = MFMA16(xa1, wih[0][ni][1], z);
            z = MFMA16(ha0, whh[0][ni][0], z);
            z = MFMA16(ha1, whh[0][ni][1], z);
            acc[ni] = z;
        }
        // prefetch next step's x while trans/barrier run
        int tn = (t + 1 < T_LEN) ? t + 1 : t;
        bf16x8 nx0 = load8f(xg + ((size_t)tn * NNODES + nb + col) * HD + quad * 8);
        bf16x8 nx1 = load8f(xg + ((size_t)tn * NNODES + nb + col) * HD + 32 + quad * 8);
        #pragma unroll
        for (int r = 0; r < 4; ++r) {
            float ig = fast_sigmoid(acc[0][r] + bias[0][0]);
            float fg = fast_sigmoid(acc[1][r] + bias[0][1]);
            float gg = fast_tanh   (acc[2][r] + bias[0][2]);
            float og = fast_sigmoid(acc[3][r] + bias[0][3]);
            float cn = fg * creg[0][r] + ig * gg;
            creg[0][r] = cn;
            hA[0][cur ^ 1][quad * 4 + r][w * 16 + col] = (bf16_t)(og * fast_tanh(cn));
        }
        __syncthreads();
        // ---------- layer 1: gates = h0'*Wih1^T + h1*Whh1^T ----------
        bf16x8 pa0 = *(const bf16x8*)&hA[0][cur ^ 1][col][quad * 8];
        bf16x8 pa1 = *(const bf16x8*)&hA[0][cur ^ 1][col][32 + quad * 8];
        bf16x8 qa0 = *(const bf16x8*)&hA[1][cur][col][quad * 8];
        bf16x8 qa1 = *(const bf16x8*)&hA[1][cur][col][32 + quad * 8];
        #pragma unroll
        for (int ni = 0; ni < 4; ++ni) {
            f32x4 z = {0.f, 0.f, 0.f, 0.f};
            z = MFMA16(pa0, wih[1][ni][0], z);
            z = MFMA16(pa1, wih[1][ni][1], z);
            z = MFMA16(qa0, whh[1][ni][0], z);
            z = MFMA16(qa1, whh[1][ni][1], z);
            acc[ni] = z;
        }
        #pragma unroll
        for (int r = 0; r < 4; ++r) {
            float ig = fast_sigmoid(acc[0][r] + bias[1][0]);
            float fg = fast_sigmoid(acc[1][r] + bias[1][1]);
            float gg = fast_tanh   (acc[2][r] + bias[1][2]);
            float og = fast_sigmoid(acc[3][r] + bias[1][3]);
            float cn = fg * creg[1][r] + ig * gg;
            creg[1][r] = cn;
            hA[1][cur ^ 1][quad * 4 + r][w * 16 + col] = (bf16_t)(og * fast_tanh(cn));
        }
        __syncthreads();
        // coalesced hs store: this tile's h_t is 1024 contiguous bf16 in ws
        {
            int node = tid >> 4;
            int h4   = (tid & 15) * 4;
            bf16x4 hv = *(const bf16x4*)&hA[1][cur ^ 1][node][h4];
            *(bf16x4*)(hsw + ((size_t)(a * T_LEN + t) * NNODES + nb + node) * HD + h4) = hv;
        }
        xa0 = nx0; xa1 = nx1;
        cur ^= 1;
    }
}

// ================= kernel 2: 96 -> 12 channel mix =================
__global__ __launch_bounds__(256) void conv_reduce_kernel(
    const bf16_t* __restrict__ hsw,  // (96, N, 64)
    const float* __restrict__ cwg,   // (12, 96)
    const float* __restrict__ cbg,   // (12)
    float* __restrict__ outg)        // (12, N, 64)
{
    int flat = blockIdx.x * 256 + threadIdx.x;
    int n  = flat >> 4;
    int hq = (flat & 15) * 4;
    f32x4 acc[T_LEN];
    #pragma unroll
    for (int o = 0; o < T_LEN; ++o) {
        float b = cbg[o];                       // uniform -> scalar load
        acc[o][0] = b; acc[o][1] = b; acc[o][2] = b; acc[o][3] = b;
    }
    #pragma unroll 1
    for (int c = 0; c < NHEADS * T_LEN; ++c) {
        bf16x4 hv = *(const bf16x4*)(hsw + ((size_t)c * NNODES + n) * HD + hq);
        float h0 = (float)hv[0], h1 = (float)hv[1], h2 = (float)hv[2], h3 = (float)hv[3];
        #pragma unroll
        for (int o = 0; o < T_LEN; ++o) {
            float cv = cwg[o * (NHEADS * T_LEN) + c];  // uniform -> scalar load
            acc[o][0] += cv * h0; acc[o][1] += cv * h1;
            acc[o][2] += cv * h2; acc[o][3] += cv * h3;
        }
    }
    #pragma unroll
    for (int o = 0; o < T_LEN; ++o)
        *(f32x4*)(outg + ((size_t)o * NNODES + n) * HD + hq) = acc[o];
}

// ============ fallback: R2's proven monolithic kernel (fp32 I/O) ============
struct SmemT {
    __align__(16) bf16_t xT[T_LEN][MT][LDSP];
    __align__(16) bf16_t hA[2][2][MT][LDSP];
    __align__(16) float  cwf[T_LEN][NHEADS * T_LEN];
    __align__(16) float  cbf[T_LEN];
};

__global__ __launch_bounds__(256) void lstm_mono_kernel(
    const float* __restrict__ xg, const float* __restrict__ Wih,
    const float* __restrict__ Whh, const float* __restrict__ bih,
    const float* __restrict__ bhh, const float* __restrict__ h0g,
    const float* __restrict__ c0g, const float* __restrict__ cwg,
    const float* __restrict__ cbg, float* __restrict__ outg)
{
    __shared__ SmemT s;
    const int tid  = threadIdx.x;
    const int w    = tid >> 6;
    const int lane = tid & 63;
    const int quad = lane >> 4;
    const int col  = lane & 15;
    const int nb   = blockIdx.x * MT;

    #pragma unroll
    for (int it = 0; it < 6; ++it) {
        int ci   = it * 256 + tid;
        int e    = ci * 8;
        int t    = e >> 10;
        int node = (e >> 6) & (MT - 1);
        int f    = e & (HD - 1);
        *(bf16x8*)&s.xT[t][node][f] =
            load8f(xg + ((size_t)t * NNODES + nb + node) * HD + f);
    }
    for (int i = tid; i < T_LEN * NHEADS * T_LEN; i += 256)
        s.cwf[i / 96][i % 96] = cwg[i];
    if (tid < T_LEN) s.cbf[tid] = cbg[tid];

    float conv_acc[T_LEN][4];
    #pragma unroll
    for (int o = 0; o < T_LEN; ++o)
        #pragma unroll
        for (int r = 0; r < 4; ++r) conv_acc[o][r] = 0.0f;

    #pragma unroll 1
    for (int a = 0; a < NHEADS; ++a) {
        bf16x8 wih[2][4][2], whh[2][4][2];
        #pragma unroll
        for (int l = 0; l < 2; ++l)
            #pragma unroll
            for (int ni = 0; ni < 4; ++ni)
                #pragma unroll
                for (int kf = 0; kf < 2; ++kf) {
                    size_t off = (((size_t)l * NHEADS + a) * 256 + (4 * ni + w) * 16 + col) * HD
                               + kf * 32 + quad * 8;
                    wih[l][ni][kf] = load8f(Wih + off);
                    whh[l][ni][kf] = load8f(Whh + off);
                }
        float bias[2][4];
        #pragma unroll
        for (int l = 0; l < 2; ++l)
            #pragma unroll
            for (int ni = 0; ni < 4; ++ni) {
                int off = (l * NHEADS + a) * 256 + ni * 64 + w * 16 + col;
                bias[l][ni] = bih[off] + bhh[off];
            }
        float creg[2][4];
        #pragma unroll
        for (int l = 0; l < 2; ++l)
            #pragma unroll
            for (int r = 0; r < 4; ++r)
                creg[l][r] = c0g[(((size_t)a * 2 + l) * NNODES + nb + quad * 4 + r) * HD
                                 + w * 16 + col];
        {
            int e    = tid * 8;
            int l    = e >> 10;
            int node = (e >> 6) & (MT - 1);
            int hh   = e & (HD - 1);
            *(bf16x8*)&s.hA[l][0][node][hh] =
                load8f(h0g + (((size_t)a * 2 + l) * NNODES + nb + node) * HD + hh);
        }
        __syncthreads();

        int cur = 0;
        #pragma unroll 1
        for (int t = 0; t < T_LEN; ++t) {
            bf16x8 xa0 = *(const bf16x8*)&s.xT[t][col][quad * 8];
            bf16x8 xa1 = *(const bf16x8*)&s.xT[t][col][32 + quad * 8];
            bf16x8 ha0 = *(const bf16x8*)&s.hA[0][cur][col][quad * 8];
            bf16x8 ha1 = *(const bf16x8*)&s.hA[0][cur][col][32 + quad * 8];
            f32x4 acc[4];
            #pragma unroll
            for (int ni = 0; ni < 4; ++ni) {
                f32x4 z = {0.f, 0.f, 0.f, 0.f};
                z = MFMA16(xa0, wih[0][ni][0], z);
                z = MFMA16(xa1, wih[0][ni][1], z);
                z = MFMA16(ha0, whh[0][ni][0], z);
                z = MFMA16(ha1, whh[0][ni][1], z);
                acc[ni] = z;
            }
            #pragma unroll
            for (int r = 0; r < 4; ++r) {
                float ig = fast_sigmoid(acc[0][r] + bias[0][0]);
                float fg = fast_sigmoid(acc[1][r] + bias[0][1]);
                float gg = fast_tanh   (acc[2][r] + bias[0][2]);
                float og = fast_sigmoid(acc[3][r] + bias[0][3]);
                float cn = fg * creg[0][r] + ig * gg;
                creg[0][r] = cn;
                s.hA[0][cur ^ 1][quad * 4 + r][w * 16 + col] = (bf16_t)(og * fast_tanh(cn));
            }
            __syncthreads();
            bf16x8 pa0 = *(const bf16x8*)&s.hA[0][cur ^ 1][col][quad * 8];
            bf16x8 pa1 = *(const bf16x8*)&s.hA[0][cur ^ 1][col][32 + quad * 8];
            bf16x8 qa0 = *(const bf16x8*)&s.hA[1][cur][col][quad * 8];
            bf16x8 qa1 = *(const bf16x8*)&s.hA[1][cur][col][32 + quad * 8];
            #pragma unroll
            for (int ni = 0; ni < 4; ++ni) {
                f32x4 z = {0.f, 0.f, 0.f, 0.f};
                z = MFMA16(pa0, wih[1][ni][0], z);
                z = MFMA16(pa1, wih[1][ni][1], z);
                z = MFMA16(qa0, whh[1][ni][0], z);
                z = MFMA16(qa1, whh[1][ni][1], z);
                acc[ni] = z;
            }
            float hn[4];
            #pragma unroll
            for (int r = 0; r < 4; ++r) {
                float ig = fast_sigmoid(acc[0][r] + bias[1][0]);
                float fg = fast_sigmoid(acc[1][r] + bias[1][1]);
                float gg = fast_tanh   (acc[2][r] + bias[1][2]);
                float og = fast_sigmoid(acc[3][r] + bias[1][3]);
                float cn = fg * creg[1][r] + ig * gg;
                creg[1][r] = cn;
                hn[r] = og * fast_tanh(cn);
                s.hA[1][cur ^ 1][quad * 4 + r][w * 16 + col] = (bf16_t)hn[r];
            }
            #pragma unroll
            for (int o = 0; o < T_LEN; ++o) {
                float cv = s.cwf[o][a * T_LEN + t];
                #pragma unroll
                for (int r = 0; r < 4; ++r) conv_acc[o][r] += cv * hn[r];
            }
            __syncthreads();
            cur ^= 1;
        }
    }
    #pragma unroll
    for (int o = 0; o < T_LEN; ++o)
        #pragma unroll
        for (int r = 0; r < 4; ++r)
            outg[((size_t)o * NNODES + nb + quad * 4 + r) * HD + w * 16 + col] =
                conv_acc[o][r] + s.cbf[o];
}

extern "C" void kernel_launch(void* const* d_in, const int* in_sizes, int n_in,
                              void* d_out, int out_size, void* d_ws, size_t ws_size,
                              hipStream_t stream) {
    (void)in_sizes; (void)n_in; (void)out_size;
    const float* x   = (const float*)d_in[0];
    const float* Wih = (const float*)d_in[1];
    const float* Whh = (const float*)d_in[2];
    const float* bih = (const float*)d_in[3];
    const float* bhh = (const float*)d_in[4];
    const float* h0  = (const float*)d_in[5];
    const float* c0  = (const float*)d_in[6];
    const float* cw  = (const float*)d_in[7];
    const float* cb  = (const float*)d_in[8];
    const size_t hs_bytes = (size_t)NHEADS * T_LEN * NNODES * HD * sizeof(bf16_t);
    if (ws_size >= hs_bytes) {
        lstm_head_kernel<<<dim3((NNODES / MT) * NHEADS), dim3(256), 0, stream>>>(
            x, Wih, Whh, bih, bhh, h0, c0, (bf16_t*)d_ws);
        conv_reduce_kernel<<<dim3(NNODES * HD / 4 / 256), dim3(256), 0, stream>>>(
            (const bf16_t*)d_ws, cw, cb, (float*)d_out);
    } else {
        lstm_mono_kernel<<<dim3(NNODES / MT), dim3(256), 0, stream>>>(
            x, Wih, Whh, bih, bhh, h0, c0, cw, cb, (float*)d_out);
    }
}

// Round 4
// 731.059 us; speedup vs baseline: 1.5631x; 1.5631x over previous
//
#include <hip/hip_runtime.h>
#include <hip/hip_bf16.h>

// LSTMblock: 2-layer, 8-head LSTM (H=F=64, T=12) over N=16384 independent
// nodes, then 1x1 conv mixing (head,t) channels (96 -> 12). fp32 I/O,
// bf16 MFMA, fp32 cell math.
//
// R4: the t-loop is barrier-latency-bound (R3: 70% idle, VALUBusy 29%).
// Changes: (1) x tile staged to LDS once per block -> NO global loads inside
// the t-loop, so the compiler's s_waitcnt before each s_barrier drains LDS
// (~120cyc) not HBM (~900cyc); (2) activations keep exact exp-based math but
// share one v_rcp across 4 denominators (trans-pipe is the top issue cost);
// (3) __launch_bounds__(256,3) pins >=3 waves/SIMD.
//
// MFMA v_mfma_f32_16x16x32_bf16 lane mapping (m89/m120-verified):
//   A[m][k]: lane(quad,col) reg j holds A[m=col][k=quad*8+j]
//   B[k][n]: lane reg j holds B[k=quad*8+j][n=col]
//   D[m][n]: lane reg r holds D[m=quad*4+r][n=col]

#define T_LEN 12
#define NHEADS 8
#define HD 64
#define NNODES 16384
#define MT 16
#define LDSP 72

typedef __bf16 bf16_t;
typedef __attribute__((ext_vector_type(4))) __bf16 bf16x4;
typedef __attribute__((ext_vector_type(8))) __bf16 bf16x8;
typedef __attribute__((ext_vector_type(4))) float f32x4;

#define MFMA16(a, b, c) __builtin_amdgcn_mfma_f32_16x16x32_bf16((a), (b), (c), 0, 0, 0)

__device__ __forceinline__ float fast_sigmoid(float v) {
    return __builtin_amdgcn_rcpf(1.0f + __expf(-v));
}
__device__ __forceinline__ float fast_tanh(float v) {
    return 2.0f * __builtin_amdgcn_rcpf(1.0f + __expf(-2.0f * v)) - 1.0f;
}

__device__ __forceinline__ bf16x8 load8f(const float* p) {
    f32x4 a = *(const f32x4*)p;
    f32x4 b = *(const f32x4*)(p + 4);
    bf16x8 r;
    r[0] = (bf16_t)a[0]; r[1] = (bf16_t)a[1]; r[2] = (bf16_t)a[2]; r[3] = (bf16_t)a[3];
    r[4] = (bf16_t)b[0]; r[5] = (bf16_t)b[1]; r[6] = (bf16_t)b[2]; r[7] = (bf16_t)b[3];
    return r;
}

// Batched LSTM gate pointwise for one row: one v_rcp serves 4 denominators.
// Exact algebra: 1/di = rif*df etc. Returns new c; writes h (pre-tanh(c) pieces
// handled by caller via the c-batch).
struct Gates { float sig_i, sig_f, tanh_g, sig_o; };
__device__ __forceinline__ Gates gate_eval(float gi, float gf, float gg, float go) {
    float ei = __expf(-gi), ef = __expf(-gf), eg = __expf(-2.0f * gg), eo = __expf(-go);
    float di = 1.0f + ei, df = 1.0f + ef, dg = 1.0f + eg, do_ = 1.0f + eo;
    float pif = di * df, pgo = dg * do_;
    float rr  = __builtin_amdgcn_rcpf(pif * pgo);
    float rif = rr * pgo, rgo = rr * pif;
    Gates g;
    g.sig_i  = rif * df;
    g.sig_f  = rif * di;
    g.tanh_g = 2.0f * (rgo * do_) - 1.0f;
    g.sig_o  = rgo * dg;
    return g;
}

// 4-way batched tanh: tanh(x_r) = 2/(1+exp(-2 x_r)) - 1 with one shared rcp.
__device__ __forceinline__ void tanh4(const float x[4], float out[4]) {
    float d0 = 1.0f + __expf(-2.0f * x[0]);
    float d1 = 1.0f + __expf(-2.0f * x[1]);
    float d2 = 1.0f + __expf(-2.0f * x[2]);
    float d3 = 1.0f + __expf(-2.0f * x[3]);
    float p01 = d0 * d1, p23 = d2 * d3;
    float rr  = __builtin_amdgcn_rcpf(p01 * p23);
    float r01 = rr * p23, r23 = rr * p01;
    out[0] = 2.0f * (r01 * d1) - 1.0f;
    out[1] = 2.0f * (r01 * d0) - 1.0f;
    out[2] = 2.0f * (r23 * d3) - 1.0f;
    out[3] = 2.0f * (r23 * d2) - 1.0f;
}

// ================= kernel 1: per-(tile,head) 2-layer LSTM =================
__global__ __launch_bounds__(256, 3) void lstm_head_kernel(
    const float* __restrict__ xg,   // (T, N, 64)
    const float* __restrict__ Wih,  // (2, 8, 256, 64)
    const float* __restrict__ Whh,  // (2, 8, 256, 64)
    const float* __restrict__ bih,  // (2, 8, 256)
    const float* __restrict__ bhh,  // (2, 8, 256)
    const float* __restrict__ h0g,  // (8, 2, N, 64)
    const float* __restrict__ c0g,  // (8, 2, N, 64)
    bf16_t* __restrict__ hsw)       // (8*T, N, 64) channel-major hs
{
    __shared__ __align__(16) bf16_t xT[T_LEN][MT][LDSP];   // x tile, A-layout
    __shared__ __align__(16) bf16_t hA[2][2][MT][LDSP];    // [layer][buf][node][h]

    const int tid  = threadIdx.x;
    const int w    = tid >> 6;     // wave id: owns gate n-tiles {w,4+w,8+w,12+w}
    const int lane = tid & 63;
    const int quad = lane >> 4;
    const int col  = lane & 15;
    const int a    = blockIdx.x & (NHEADS - 1);
    const int nb   = (blockIdx.x >> 3) * MT;

    // ---- one-time staging: x tile into LDS (coalesced, 1536 8-elem chunks) ----
    #pragma unroll
    for (int it = 0; it < 6; ++it) {
        int ci   = it * 256 + tid;
        int e    = ci * 8;
        int t    = e >> 10;
        int node = (e >> 6) & (MT - 1);
        int f    = e & (HD - 1);
        *(bf16x8*)&xT[t][node][f] =
            load8f(xg + ((size_t)t * NNODES + nb + node) * HD + f);
    }
    // h0 -> hA[*][0]
    {
        int e    = tid * 8;
        int l    = e >> 10;
        int node = (e >> 6) & (MT - 1);
        int hh   = e & (HD - 1);
        *(bf16x8*)&hA[l][0][node][hh] =
            load8f(h0g + (((size_t)a * 2 + l) * NNODES + nb + node) * HD + hh);
    }

    // ---- per-head weight B-fragments, register-resident ----
    bf16x8 wih[2][4][2], whh[2][4][2];   // [layer][gate i/f/g/o][kfrag]
    #pragma unroll
    for (int l = 0; l < 2; ++l)
        #pragma unroll
        for (int ni = 0; ni < 4; ++ni)
            #pragma unroll
            for (int kf = 0; kf < 2; ++kf) {
                size_t off = (((size_t)l * NHEADS + a) * 256 + (4 * ni + w) * 16 + col) * HD
                           + kf * 32 + quad * 8;
                wih[l][ni][kf] = load8f(Wih + off);
                whh[l][ni][kf] = load8f(Whh + off);
            }
    float bias[2][4];
    #pragma unroll
    for (int l = 0; l < 2; ++l)
        #pragma unroll
        for (int ni = 0; ni < 4; ++ni) {
            int off = (l * NHEADS + a) * 256 + ni * 64 + w * 16 + col;
            bias[l][ni] = bih[off] + bhh[off];
        }
    float creg[2][4];
    #pragma unroll
    for (int l = 0; l < 2; ++l)
        #pragma unroll
        for (int r = 0; r < 4; ++r)
            creg[l][r] = c0g[(((size_t)a * 2 + l) * NNODES + nb + quad * 4 + r) * HD
                             + w * 16 + col];
    __syncthreads();

    int cur = 0;
    #pragma unroll 1
    for (int t = 0; t < T_LEN; ++t) {
        // ---------- layer 0: gates = x_t*Wih0^T + h0*Whh0^T ----------
        bf16x8 xa0 = *(const bf16x8*)&xT[t][col][quad * 8];
        bf16x8 xa1 = *(const bf16x8*)&xT[t][col][32 + quad * 8];
        bf16x8 ha0 = *(const bf16x8*)&hA[0][cur][col][quad * 8];
        bf16x8 ha1 = *(const bf16x8*)&hA[0][cur][col][32 + quad * 8];
        f32x4 acc[4];
        #pragma unroll
        for (int ni = 0; ni < 4; ++ni) {
            f32x4 z = {0.f, 0.f, 0.f, 0.f};
            z = MFMA16(xa0, wih[0][ni][0], z);
            z = MFMA16(xa1, wih[0][ni][1], z);
            z = MFMA16(ha0, whh[0][ni][0], z);
            z = MFMA16(ha1, whh[0][ni][1], z);
            acc[ni] = z;
        }
        {
            float cn[4], tc[4], so[4];
            #pragma unroll
            for (int r = 0; r < 4; ++r) {
                Gates g = gate_eval(acc[0][r] + bias[0][0], acc[1][r] + bias[0][1],
                                    acc[2][r] + bias[0][2], acc[3][r] + bias[0][3]);
                cn[r] = g.sig_f * creg[0][r] + g.sig_i * g.tanh_g;
                so[r] = g.sig_o;
                creg[0][r] = cn[r];
            }
            tanh4(cn, tc);
            #pragma unroll
            for (int r = 0; r < 4; ++r)
                hA[0][cur ^ 1][quad * 4 + r][w * 16 + col] = (bf16_t)(so[r] * tc[r]);
        }
        __syncthreads();
        // ---------- layer 1: gates = h0'*Wih1^T + h1*Whh1^T ----------
        bf16x8 pa0 = *(const bf16x8*)&hA[0][cur ^ 1][col][quad * 8];
        bf16x8 pa1 = *(const bf16x8*)&hA[0][cur ^ 1][col][32 + quad * 8];
        bf16x8 qa0 = *(const bf16x8*)&hA[1][cur][col][quad * 8];
        bf16x8 qa1 = *(const bf16x8*)&hA[1][cur][col][32 + quad * 8];
        #pragma unroll
        for (int ni = 0; ni < 4; ++ni) {
            f32x4 z = {0.f, 0.f, 0.f, 0.f};
            z = MFMA16(pa0, wih[1][ni][0], z);
            z = MFMA16(pa1, wih[1][ni][1], z);
            z = MFMA16(qa0, whh[1][ni][0], z);
            z = MFMA16(qa1, whh[1][ni][1], z);
            acc[ni] = z;
        }
        {
            float cn[4], tc[4], so[4];
            #pragma unroll
            for (int r = 0; r < 4; ++r) {
                Gates g = gate_eval(acc[0][r] + bias[1][0], acc[1][r] + bias[1][1],
                                    acc[2][r] + bias[1][2], acc[3][r] + bias[1][3]);
                cn[r] = g.sig_f * creg[1][r] + g.sig_i * g.tanh_g;
                so[r] = g.sig_o;
                creg[1][r] = cn[r];
            }
            tanh4(cn, tc);
            #pragma unroll
            for (int r = 0; r < 4; ++r)
                hA[1][cur ^ 1][quad * 4 + r][w * 16 + col] = (bf16_t)(so[r] * tc[r]);
        }
        __syncthreads();
        // coalesced hs store (issued ~a full step before the next vm drain)
        {
            int node = tid >> 4;
            int h4   = (tid & 15) * 4;
            bf16x4 hv = *(const bf16x4*)&hA[1][cur ^ 1][node][h4];
            *(bf16x4*)(hsw + ((size_t)(a * T_LEN + t) * NNODES + nb + node) * HD + h4) = hv;
        }
        cur ^= 1;
    }
}

// ================= kernel 2: 96 -> 12 channel mix =================
__global__ __launch_bounds__(256) void conv_reduce_kernel(
    const bf16_t* __restrict__ hsw,  // (96, N, 64)
    const float* __restrict__ cwg,   // (12, 96)
    const float* __restrict__ cbg,   // (12)
    float* __restrict__ outg)        // (12, N, 64)
{
    int flat = blockIdx.x * 256 + threadIdx.x;
    int n  = flat >> 4;
    int hq = (flat & 15) * 4;
    f32x4 acc[T_LEN];
    #pragma unroll
    for (int o = 0; o < T_LEN; ++o) {
        float b = cbg[o];
        acc[o][0] = b; acc[o][1] = b; acc[o][2] = b; acc[o][3] = b;
    }
    #pragma unroll 1
    for (int c = 0; c < NHEADS * T_LEN; ++c) {
        bf16x4 hv = *(const bf16x4*)(hsw + ((size_t)c * NNODES + n) * HD + hq);
        float h0 = (float)hv[0], h1 = (float)hv[1], h2 = (float)hv[2], h3 = (float)hv[3];
        #pragma unroll
        for (int o = 0; o < T_LEN; ++o) {
            float cv = cwg[o * (NHEADS * T_LEN) + c];
            acc[o][0] += cv * h0; acc[o][1] += cv * h1;
            acc[o][2] += cv * h2; acc[o][3] += cv * h3;
        }
    }
    #pragma unroll
    for (int o = 0; o < T_LEN; ++o)
        *(f32x4*)(outg + ((size_t)o * NNODES + n) * HD + hq) = acc[o];
}

// ============ fallback: R2's proven monolithic kernel (fp32 I/O) ============
struct SmemT {
    __align__(16) bf16_t xT[T_LEN][MT][LDSP];
    __align__(16) bf16_t hA[2][2][MT][LDSP];
    __align__(16) float  cwf[T_LEN][NHEADS * T_LEN];
    __align__(16) float  cbf[T_LEN];
};

__global__ __launch_bounds__(256) void lstm_mono_kernel(
    const float* __restrict__ xg, const float* __restrict__ Wih,
    const float* __restrict__ Whh, const float* __restrict__ bih,
    const float* __restrict__ bhh, const float* __restrict__ h0g,
    const float* __restrict__ c0g, const float* __restrict__ cwg,
    const float* __restrict__ cbg, float* __restrict__ outg)
{
    __shared__ SmemT s;
    const int tid  = threadIdx.x;
    const int w    = tid >> 6;
    const int lane = tid & 63;
    const int quad = lane >> 4;
    const int col  = lane & 15;
    const int nb   = blockIdx.x * MT;

    #pragma unroll
    for (int it = 0; it < 6; ++it) {
        int ci   = it * 256 + tid;
        int e    = ci * 8;
        int t    = e >> 10;
        int node = (e >> 6) & (MT - 1);
        int f    = e & (HD - 1);
        *(bf16x8*)&s.xT[t][node][f] =
            load8f(xg + ((size_t)t * NNODES + nb + node) * HD + f);
    }
    for (int i = tid; i < T_LEN * NHEADS * T_LEN; i += 256)
        s.cwf[i / 96][i % 96] = cwg[i];
    if (tid < T_LEN) s.cbf[tid] = cbg[tid];

    float conv_acc[T_LEN][4];
    #pragma unroll
    for (int o = 0; o < T_LEN; ++o)
        #pragma unroll
        for (int r = 0; r < 4; ++r) conv_acc[o][r] = 0.0f;

    #pragma unroll 1
    for (int a = 0; a < NHEADS; ++a) {
        bf16x8 wih[2][4][2], whh[2][4][2];
        #pragma unroll
        for (int l = 0; l < 2; ++l)
            #pragma unroll
            for (int ni = 0; ni < 4; ++ni)
                #pragma unroll
                for (int kf = 0; kf < 2; ++kf) {
                    size_t off = (((size_t)l * NHEADS + a) * 256 + (4 * ni + w) * 16 + col) * HD
                               + kf * 32 + quad * 8;
                    wih[l][ni][kf] = load8f(Wih + off);
                    whh[l][ni][kf] = load8f(Whh + off);
                }
        float bias[2][4];
        #pragma unroll
        for (int l = 0; l < 2; ++l)
            #pragma unroll
            for (int ni = 0; ni < 4; ++ni) {
                int off = (l * NHEADS + a) * 256 + ni * 64 + w * 16 + col;
                bias[l][ni] = bih[off] + bhh[off];
            }
        float creg[2][4];
        #pragma unroll
        for (int l = 0; l < 2; ++l)
            #pragma unroll
            for (int r = 0; r < 4; ++r)
                creg[l][r] = c0g[(((size_t)a * 2 + l) * NNODES + nb + quad * 4 + r) * HD
                                 + w * 16 + col];
        {
            int e    = tid * 8;
            int l    = e >> 10;
            int node = (e >> 6) & (MT - 1);
            int hh   = e & (HD - 1);
            *(bf16x8*)&s.hA[l][0][node][hh] =
                load8f(h0g + (((size_t)a * 2 + l) * NNODES + nb + node) * HD + hh);
        }
        __syncthreads();

        int cur = 0;
        #pragma unroll 1
        for (int t = 0; t < T_LEN; ++t) {
            bf16x8 xa0 = *(const bf16x8*)&s.xT[t][col][quad * 8];
            bf16x8 xa1 = *(const bf16x8*)&s.xT[t][col][32 + quad * 8];
            bf16x8 ha0 = *(const bf16x8*)&s.hA[0][cur][col][quad * 8];
            bf16x8 ha1 = *(const bf16x8*)&s.hA[0][cur][col][32 + quad * 8];
            f32x4 acc[4];
            #pragma unroll
            for (int ni = 0; ni < 4; ++ni) {
                f32x4 z = {0.f, 0.f, 0.f, 0.f};
                z = MFMA16(xa0, wih[0][ni][0], z);
                z = MFMA16(xa1, wih[0][ni][1], z);
                z = MFMA16(ha0, whh[0][ni][0], z);
                z = MFMA16(ha1, whh[0][ni][1], z);
                acc[ni] = z;
            }
            #pragma unroll
            for (int r = 0; r < 4; ++r) {
                float ig = fast_sigmoid(acc[0][r] + bias[0][0]);
                float fg = fast_sigmoid(acc[1][r] + bias[0][1]);
                float gg = fast_tanh   (acc[2][r] + bias[0][2]);
                float og = fast_sigmoid(acc[3][r] + bias[0][3]);
                float cn = fg * creg[0][r] + ig * gg;
                creg[0][r] = cn;
                s.hA[0][cur ^ 1][quad * 4 + r][w * 16 + col] = (bf16_t)(og * fast_tanh(cn));
            }
            __syncthreads();
            bf16x8 pa0 = *(const bf16x8*)&s.hA[0][cur ^ 1][col][quad * 8];
            bf16x8 pa1 = *(const bf16x8*)&s.hA[0][cur ^ 1][col][32 + quad * 8];
            bf16x8 qa0 = *(const bf16x8*)&s.hA[1][cur][col][quad * 8];
            bf16x8 qa1 = *(const bf16x8*)&s.hA[1][cur][col][32 + quad * 8];
            #pragma unroll
            for (int ni = 0; ni < 4; ++ni) {
                f32x4 z = {0.f, 0.f, 0.f, 0.f};
                z = MFMA16(pa0, wih[1][ni][0], z);
                z = MFMA16(pa1, wih[1][ni][1], z);
                z = MFMA16(qa0, whh[1][ni][0], z);
                z = MFMA16(qa1, whh[1][ni][1], z);
                acc[ni] = z;
            }
            float hn[4];
            #pragma unroll
            for (int r = 0; r < 4; ++r) {
                float ig = fast_sigmoid(acc[0][r] + bias[1][0]);
                float fg = fast_sigmoid(acc[1][r] + bias[1][1]);
                float gg = fast_tanh   (acc[2][r] + bias[1][2]);
                float og = fast_sigmoid(acc[3][r] + bias[1][3]);
                float cn = fg * creg[1][r] + ig * gg;
                creg[1][r] = cn;
                hn[r] = og * fast_tanh(cn);
                s.hA[1][cur ^ 1][quad * 4 + r][w * 16 + col] = (bf16_t)hn[r];
            }
            #pragma unroll
            for (int o = 0; o < T_LEN; ++o) {
                float cv = s.cwf[o][a * T_LEN + t];
                #pragma unroll
                for (int r = 0; r < 4; ++r) conv_acc[o][r] += cv * hn[r];
            }
            __syncthreads();
            cur ^= 1;
        }
    }
    #pragma unroll
    for (int o = 0; o < T_LEN; ++o)
        #pragma unroll
        for (int r = 0; r < 4; ++r)
            outg[((size_t)o * NNODES + nb + quad * 4 + r) * HD + w * 16 + col] =
                conv_acc[o][r] + s.cbf[o];
}

extern "C" void kernel_launch(void* const* d_in, const int* in_sizes, int n_in,
                              void* d_out, int out_size, void* d_ws, size_t ws_size,
                              hipStream_t stream) {
    (void)in_sizes; (void)n_in; (void)out_size;
    const float* x   = (const float*)d_in[0];
    const float* Wih = (const float*)d_in[1];
    const float* Whh = (const float*)d_in[2];
    const float* bih = (const float*)d_in[3];
    const float* bhh = (const float*)d_in[4];
    const float* h0  = (const float*)d_in[5];
    const float* c0  = (const float*)d_in[6];
    const float* cw  = (const float*)d_in[7];
    const float* cb  = (const float*)d_in[8];
    const size_t hs_bytes = (size_t)NHEADS * T_LEN * NNODES * HD * sizeof(bf16_t);
    if (ws_size >= hs_bytes) {
        lstm_head_kernel<<<dim3((NNODES / MT) * NHEADS), dim3(256), 0, stream>>>(
            x, Wih, Whh, bih, bhh, h0, c0, (bf16_t*)d_ws);
        conv_reduce_kernel<<<dim3(NNODES * HD / 4 / 256), dim3(256), 0, stream>>>(
            (const bf16_t*)d_ws, cw, cb, (float*)d_out);
    } else {
        lstm_mono_kernel<<<dim3(NNODES / MT), dim3(256), 0, stream>>>(
            x, Wih, Whh, bih, bhh, h0, c0, cw, cb, (float*)d_out);
    }
}